// Round 5
// baseline (3520.396 us; speedup 1.0000x reference)
//
#include <hip/hip_runtime.h>
#include <hip/hip_fp16.h>

// HyperScatteringModule: V=65536, E=16384, NNZ=1048576, F=128
#define FEAT 128
#define NSLICE 4
#define SLICE_DW 16  // dwords per row-slice (32 fp16 feats = 64 B = one cache line)

// ---------------- fp16 helpers (packed pairs: lo = even feat) ----------------

__device__ inline float hlo(unsigned u) {
    unsigned short s = (unsigned short)(u & 0xFFFFu);
    __half h = *(__half*)&s;
    return __half2float(h);
}
__device__ inline float hhi(unsigned u) {
    unsigned short s = (unsigned short)(u >> 16);
    __half h = *(__half*)&s;
    return __half2float(h);
}
__device__ inline unsigned hpack(float a, float b) {
    __half ha = __float2half_rn(a), hb = __float2half_rn(b);
    unsigned short ua = *(unsigned short*)&ha, ub = *(unsigned short*)&hb;
    return (unsigned)ua | ((unsigned)ub << 16);
}
__device__ inline unsigned pkadd(unsigned a, unsigned b) {
    __half2 ha = *(__half2*)&a, hb = *(__half2*)&b;
    __half2 r = __hadd2(ha, hb);
    return *(unsigned*)&r;
}

// ---------------- CSR build ----------------

__global__ void count_deg(const int* __restrict__ vids, const int* __restrict__ eids,
                          int* __restrict__ deg_v, int* __restrict__ deg_e, int nnz) {
    int n = blockIdx.x * blockDim.x + threadIdx.x;
    if (n < nnz) {
        atomicAdd(&deg_v[vids[n]], 1);
        atomicAdd(&deg_e[eids[n]], 1);
    }
}

// Simple single-block exclusive scan (unpadded). off/cur offsets, inv = 1/deg.
template <int N, int T>
__global__ __launch_bounds__(T) void scan_excl(const int* __restrict__ deg,
                                               int* __restrict__ off,
                                               int* __restrict__ cur,
                                               float* __restrict__ inv) {
    __shared__ int partial[T];
    const int per = N / T;
    int tid = threadIdx.x;
    int base = tid * per;
    int s = 0;
    for (int i = 0; i < per; ++i) s += deg[base + i];
    partial[tid] = s;
    __syncthreads();
    for (int dd = 1; dd < T; dd <<= 1) {
        int add = (tid >= dd) ? partial[tid - dd] : 0;
        __syncthreads();
        partial[tid] += add;
        __syncthreads();
    }
    int run = (tid > 0) ? partial[tid - 1] : 0;
    for (int i = 0; i < per; ++i) {
        int d = deg[base + i];
        off[base + i] = run;
        cur[base + i] = run;
        inv[base + i] = (d > 0) ? (1.0f / (float)d) : 0.0f;
        run += d;
    }
    if (tid == T - 1) off[N] = run;
}

__global__ void fill_csr(const int* __restrict__ vids, const int* __restrict__ eids,
                         int* __restrict__ cur_v, int* __restrict__ cur_e,
                         unsigned short* __restrict__ v_nbr16,
                         unsigned short* __restrict__ e_nbr16, int nnz) {
    int n = blockIdx.x * blockDim.x + threadIdx.x;
    if (n < nnz) {
        int v = vids[n], e = eids[n];
        int p = atomicAdd(&cur_e[e], 1);
        e_nbr16[p] = (unsigned short)v;   // vertex index 0..65535
        int q = atomicAdd(&cur_v[v], 1);
        v_nbr16[q] = (unsigned short)e;   // edge index 0..16383
    }
}

// ---------------- prescale: xs4[sl][v][d] = fp16x2(X[v, sl*32+2d .. +1] * inv_v) ----------------
__global__ __launch_bounds__(256) void prescale(const float* __restrict__ X,
                                                const float* __restrict__ inv_v,
                                                unsigned* __restrict__ xs4, int V) {
    int tid = blockIdx.x * 256 + threadIdx.x;  // over V*64 dwords
    int v = tid >> 6, k = tid & 63, sl = k >> 4, d = k & 15;
    float sc = inv_v[v];
    float2 x = *(const float2*)(X + (size_t)v * FEAT + sl * 32 + 2 * d);
    xs4[(size_t)sl * ((size_t)V * SLICE_DW) + (size_t)v * SLICE_DW + d] =
        hpack(x.x * sc, x.y * sc);
}

// ---------------- sliced segment gather-sum ----------------
// grid = (nseg/16, NSLICE). Each 16-lane group owns one segment; lane owns one
// dword (2 feats) of the 64B row-slice. Unpadded CSR; masked iterations use
// dummy index 0 and are exactly compensated by acc -= nmask * src_row0.
// dst[seg] = fp16(scale[seg] * sum_{u in nbr} src[u]); optional ckpt copy.
__global__ __launch_bounds__(256) void gather_slice(
    const unsigned* __restrict__ srcB, unsigned srcStride,  // dwords per slice
    unsigned* __restrict__ dstB, unsigned dstStride,
    const int* __restrict__ offs, const unsigned short* __restrict__ nbr,
    const float* __restrict__ scale,
    unsigned* __restrict__ ckptB,  // (unsigned*)out + slot*256, or nullptr
    int nseg) {
    const int sl = blockIdx.y;
    const unsigned* src = srcB + (size_t)sl * srcStride;
    unsigned* dst = dstB + (size_t)sl * dstStride;
    int lane = threadIdx.x & 63;
    int grp = lane >> 4;
    int d = lane & 15;
    int seg = (blockIdx.x * 4 + (threadIdx.x >> 6)) * 4 + grp;
    int p = offs[seg];
    int deg = offs[seg + 1] - p;
    // wave-uniform trip count = max deg over the wave's 4 segments
    int m = deg;
    m = max(m, __shfl_xor(m, 16, 64));
    m = max(m, __shfl_xor(m, 32, 64));
    unsigned x0 = src[d];  // row 0, for masked-iteration compensation
    unsigned acc = 0u;
    for (int t = 0; t < m; ++t) {
        unsigned idx = (t < deg) ? (unsigned)nbr[p + t] : 0u;
        acc = pkadd(acc, src[(size_t)idx * SLICE_DW + d]);
    }
    // exact compensation: masked iterations each added src_row0
    {
        __half2 c = __float2half2_rn((float)(m - deg));
        __half2 a = *(__half2*)&acc;
        __half2 x = *(__half2*)&x0;
        a = __hsub2(a, __hmul2(c, x));
        acc = *(unsigned*)&a;
    }
    float sc = scale[seg];
    unsigned pk = hpack(hlo(acc) * sc, hhi(acc) * sc);
    dst[(size_t)seg * SLICE_DW + d] = pk;
    if (ckptB) ckptB[(size_t)seg * 1536 + (size_t)sl * SLICE_DW + d] = pk;
}

// ---------------- final wavelet combine + relu split ----------------
// Checkpoints: fp16(inv_v*L) at out dwords v*1536 + slot*256 + sl*16 + [0,16).
// Recover L = ckpt * deg_v. 256 threads = 8 vertices, 4 feats/thread.
__global__ __launch_bounds__(256) void wavelet_out(const float* __restrict__ X,
                                                   const int* __restrict__ deg_v,
                                                   float* __restrict__ out) {
    int tid = blockIdx.x * 256 + threadIdx.x;
    int v = tid >> 5;
    int f4 = (tid & 31) * 4;           // feats f4..f4+3
    int sl = f4 >> 5;                  // feature slice
    int dl = (f4 & 31) >> 1;           // dword within slice (2 dwords cover 4 feats)
    float* row = out + (size_t)v * 1536;
    const unsigned* rowu = (const unsigned*)row;
    float degf = (float)deg_v[v];
    float4 L0v = *(const float4*)(X + (size_t)v * FEAT + f4);
    float l0[4] = {L0v.x, L0v.y, L0v.z, L0v.w};
    float L[5][4];
#pragma unroll
    for (int s = 0; s < 5; ++s) {
        int b = (s + 1) * 256 + sl * SLICE_DW + dl;
        unsigned d0 = rowu[b];
        unsigned d1 = rowu[b + 1];
        L[s][0] = hlo(d0) * degf;
        L[s][1] = hhi(d0) * degf;
        L[s][2] = hlo(d1) * degf;
        L[s][3] = hhi(d1) * degf;
    }
    float wv[6][4];
#pragma unroll
    for (int j = 0; j < 4; ++j) {
        wv[0][j] = l0[j] - L[0][j];
        wv[1][j] = L[0][j] - L[1][j];
        wv[2][j] = L[1][j] - L[2][j];
        wv[3][j] = L[2][j] - L[3][j];
        wv[4][j] = L[3][j] - L[4][j];
        wv[5][j] = L[4][j];
    }
    __syncthreads();
#pragma unroll
    for (int r = 0; r < 6; ++r) {
        float4 pp, mm;
        pp.x = fmaxf(wv[r][0], 0.f); mm.x = fmaxf(-wv[r][0], 0.f);
        pp.y = fmaxf(wv[r][1], 0.f); mm.y = fmaxf(-wv[r][1], 0.f);
        pp.z = fmaxf(wv[r][2], 0.f); mm.z = fmaxf(-wv[r][2], 0.f);
        pp.w = fmaxf(wv[r][3], 0.f); mm.w = fmaxf(-wv[r][3], 0.f);
        *(float4*)(row + r * 256 + f4) = pp;
        *(float4*)(row + r * 256 + 128 + f4) = mm;
    }
}

// ---------------- launch ----------------

extern "C" void kernel_launch(void* const* d_in, const int* in_sizes, int n_in,
                              void* d_out, int out_size, void* d_ws, size_t ws_size,
                              hipStream_t stream) {
    const float* X = (const float*)d_in[0];
    const int* vids = (const int*)d_in[1];
    const int* eids = (const int*)d_in[2];
    const int NNZ = in_sizes[1];       // 1048576
    const int V = in_sizes[0] / FEAT;  // 65536
    const int E = 16384;               // num_e
    float* out = (float*)d_out;

    char* w = (char*)d_ws;
    size_t o = 0;
    auto take = [&](size_t bytes) {
        void* p = (void*)(w + o);
        o = (o + bytes + 255) & ~(size_t)255;
        return p;
    };
    int* deg_v = (int*)take((size_t)(V + E) * 4);  // deg_v, deg_e contiguous
    int* deg_e = deg_v + V;
    int* off_e = (int*)take((size_t)(E + 1) * 4);
    int* off_v = (int*)take((size_t)(V + 1) * 4);
    int* cur_e = (int*)take((size_t)E * 4);
    int* cur_v = (int*)take((size_t)V * 4);
    float* inv_e = (float*)take((size_t)E * 4);
    float* inv_v = (float*)take((size_t)V * 4);
    unsigned short* e_nbr16 = (unsigned short*)take((size_t)(NNZ + 256) * 2);
    unsigned short* v_nbr16 = (unsigned short*)take((size_t)(NNZ + 256) * 2);
    unsigned* xs4 = (unsigned*)take((size_t)NSLICE * V * SLICE_DW * 4);  // 16.8 MB
    unsigned* es4 = (unsigned*)take((size_t)NSLICE * E * SLICE_DW * 4);  // 4.2 MB
    (void)ws_size;
    (void)n_in;
    (void)out_size;

    const unsigned XS_STRIDE = (unsigned)(V * SLICE_DW);
    const unsigned ES_STRIDE = (unsigned)(E * SLICE_DW);

    // 1) degrees
    hipMemsetAsync(deg_v, 0, (size_t)(V + E) * 4, stream);
    count_deg<<<(NNZ + 255) / 256, 256, 0, stream>>>(vids, eids, deg_v, deg_e, NNZ);

    // 2) offsets + cursors + inverse degrees (unpadded)
    scan_excl<16384, 1024><<<1, 1024, 0, stream>>>(deg_e, off_e, cur_e, inv_e);
    scan_excl<65536, 1024><<<1, 1024, 0, stream>>>(deg_v, off_v, cur_v, inv_v);

    // 3) adjacency lists (u16)
    fill_csr<<<(NNZ + 255) / 256, 256, 0, stream>>>(vids, eids, cur_v, cur_e,
                                                    v_nbr16, e_nbr16, NNZ);

    // 4) xs4 = fp16(X * inv_v), feature-sliced
    prescale<<<V * 64 / 256, 256, 0, stream>>>(X, inv_v, xs4, V);

    // 5) 16 diffusion steps, 4 feature slices phase-ordered via blockIdx.y.
    //    v2e: es = fp16(inv_e * sum xs);  e2v: xs = fp16(inv_v * sum es);
    //    checkpoints k in {1,2,4,8,16} also copy packed fp16 into out.
    for (int k = 1; k <= 16; ++k) {
        gather_slice<<<dim3(E / 16, NSLICE), 256, 0, stream>>>(
            xs4, XS_STRIDE, es4, ES_STRIDE, off_e, e_nbr16, inv_e, nullptr, E);
        unsigned* ck = nullptr;
        if (k == 1) ck = (unsigned*)out + 1 * 256;
        else if (k == 2) ck = (unsigned*)out + 2 * 256;
        else if (k == 4) ck = (unsigned*)out + 3 * 256;
        else if (k == 8) ck = (unsigned*)out + 4 * 256;
        else if (k == 16) ck = (unsigned*)out + 5 * 256;
        gather_slice<<<dim3(V / 16, NSLICE), 256, 0, stream>>>(
            es4, ES_STRIDE, xs4, XS_STRIDE, off_v, v_nbr16, inv_v, ck, V);
    }

    // 6) wavelet combine + relu split, in place over out
    wavelet_out<<<V * 32 / 256, 256, 0, stream>>>(X, deg_v, out);
}

// Round 6
// 2006.314 us; speedup vs baseline: 1.7547x; 1.7547x over previous
//
#include <hip/hip_runtime.h>
#include <hip/hip_fp16.h>

// HyperScatteringModule: V=65536, E=16384, NNZ=1048576, F=128
#define FEAT 128
#define NSLICE 4
#define SLICE_DW 16  // dwords per row-slice (32 fp16 feats = 64 B = one cache line)

// ---------------- fp16 helpers (packed pairs: lo = even feat) ----------------

__device__ inline float hlo(unsigned u) {
    unsigned short s = (unsigned short)(u & 0xFFFFu);
    __half h = *(__half*)&s;
    return __half2float(h);
}
__device__ inline float hhi(unsigned u) {
    unsigned short s = (unsigned short)(u >> 16);
    __half h = *(__half*)&s;
    return __half2float(h);
}
__device__ inline unsigned hpack(float a, float b) {
    __half ha = __float2half_rn(a), hb = __float2half_rn(b);
    unsigned short ua = *(unsigned short*)&ha, ub = *(unsigned short*)&hb;
    return (unsigned)ua | ((unsigned)ub << 16);
}
__device__ inline unsigned pkadd(unsigned a, unsigned b) {
    __half2 ha = *(__half2*)&a, hb = *(__half2*)&b;
    __half2 r = __hadd2(ha, hb);
    return *(unsigned*)&r;
}

// ---------------- CSR build ----------------

__global__ void count_deg(const int* __restrict__ vids, const int* __restrict__ eids,
                          int* __restrict__ deg_v, int* __restrict__ deg_e, int nnz) {
    int n = blockIdx.x * blockDim.x + threadIdx.x;
    if (n < nnz) {
        atomicAdd(&deg_v[vids[n]], 1);
        atomicAdd(&deg_e[eids[n]], 1);
    }
}

// Exclusive scan over CHUNK-padded degrees; off/cur = padded offsets, inv = 1/true_deg.
template <int N, int T, int CHUNK>
__global__ __launch_bounds__(T) void scan_pad(const int* __restrict__ deg,
                                              int* __restrict__ off,
                                              int* __restrict__ cur,
                                              float* __restrict__ inv) {
    __shared__ int partial[T];
    const int per = N / T;
    int tid = threadIdx.x;
    int base = tid * per;
    int dloc[per];
    int s = 0;
#pragma unroll
    for (int i = 0; i < per / 4; ++i) {
        int4 d4 = *(const int4*)(deg + base + 4 * i);
        dloc[4 * i] = d4.x; dloc[4 * i + 1] = d4.y;
        dloc[4 * i + 2] = d4.z; dloc[4 * i + 3] = d4.w;
        s += ((d4.x + CHUNK - 1) & ~(CHUNK - 1)) + ((d4.y + CHUNK - 1) & ~(CHUNK - 1)) +
             ((d4.z + CHUNK - 1) & ~(CHUNK - 1)) + ((d4.w + CHUNK - 1) & ~(CHUNK - 1));
    }
    partial[tid] = s;
    __syncthreads();
    for (int d = 1; d < T; d <<= 1) {
        int add = (tid >= d) ? partial[tid - d] : 0;
        __syncthreads();
        partial[tid] += add;
        __syncthreads();
    }
    int run = (tid > 0) ? partial[tid - 1] : 0;
#pragma unroll
    for (int i = 0; i < per / 4; ++i) {
        int o[4];
        float iv[4];
#pragma unroll
        for (int j = 0; j < 4; ++j) {
            int d = dloc[4 * i + j];
            o[j] = run;
            iv[j] = (d > 0) ? (1.0f / (float)d) : 0.0f;
            run += (d + CHUNK - 1) & ~(CHUNK - 1);
        }
        *(int4*)(off + base + 4 * i) = make_int4(o[0], o[1], o[2], o[3]);
        *(int4*)(cur + base + 4 * i) = make_int4(o[0], o[1], o[2], o[3]);
        *(float4*)(inv + base + 4 * i) = make_float4(iv[0], iv[1], iv[2], iv[3]);
    }
    if (tid == T - 1) off[N] = run;
}

__global__ void fill_csr(const int* __restrict__ vids, const int* __restrict__ eids,
                         int* __restrict__ cur_v, int* __restrict__ cur_e,
                         unsigned short* __restrict__ v_nbr16,
                         unsigned short* __restrict__ e_nbr16, int nnz) {
    int n = blockIdx.x * blockDim.x + threadIdx.x;
    if (n < nnz) {
        int v = vids[n], e = eids[n];
        int p = atomicAdd(&cur_e[e], 1);
        e_nbr16[p] = (unsigned short)v;   // vertex index 0..65535
        int q = atomicAdd(&cur_v[v], 1);
        v_nbr16[q] = (unsigned short)e;   // edge index 0..16383
    }
}

// ---------------- prescale: xs4[sl][v][d] = fp16x2(X[v, sl*32+2d .. +1] * inv_v) ----------------
__global__ __launch_bounds__(256) void prescale(const float* __restrict__ X,
                                                const float* __restrict__ inv_v,
                                                unsigned* __restrict__ xs4, int V) {
    int tid = blockIdx.x * 256 + threadIdx.x;  // over V*64 dwords
    int v = tid >> 6, k = tid & 63, sl = k >> 4, d = k & 15;
    float sc = inv_v[v];
    float2 x = *(const float2*)(X + (size_t)v * FEAT + sl * 32 + 2 * d);
    xs4[(size_t)sl * ((size_t)V * SLICE_DW) + (size_t)v * SLICE_DW + d] =
        hpack(x.x * sc, x.y * sc);
}

// ---------------- sliced segment gather-sum, wave per segment ----------------
// grid = (nseg/4, NSLICE), 4 waves/block. Lane-group of 16 owns one neighbor
// row (64 B slice); lane reads 1 dword. 8 neighbors per unrolled iteration:
// 2 uniform uint2 index loads + 2 wave row-loads (256 B each). CSR padded to
// multiple of 4 with index 0; compensated exactly by acc -= npad * row0.
__global__ __launch_bounds__(256) void gather_slice(
    const unsigned* __restrict__ srcB, unsigned srcStride,
    unsigned* __restrict__ dstB, unsigned dstStride,
    const int* __restrict__ offs, const int* __restrict__ tdeg,
    const unsigned short* __restrict__ nbr, const float* __restrict__ scale,
    unsigned* __restrict__ ckptB, int nseg) {
    const int sl = blockIdx.y;
    const unsigned* src = srcB + (size_t)sl * srcStride;
    unsigned* dst = dstB + (size_t)sl * dstStride;
    int seg = __builtin_amdgcn_readfirstlane(blockIdx.x * 4 + (threadIdx.x >> 6));
    int lane = threadIdx.x & 63;
    int d = lane & 15;
    bool m16 = (lane & 16) != 0;
    bool m32 = (lane & 32) != 0;
    int p0 = __builtin_amdgcn_readfirstlane(offs[seg]);
    int pe = __builtin_amdgcn_readfirstlane(offs[seg + 1]);
    int dg = __builtin_amdgcn_readfirstlane(tdeg[seg]);
    unsigned x0 = src[d];  // row 0 slice (for padding compensation)
    unsigned acc = 0u;
    int p = p0;
    for (; p + 8 <= pe; p += 8) {
        uint2 ca = *(const uint2*)(nbr + p);      // idx 0..3 (uniform addr)
        uint2 cb = *(const uint2*)(nbr + p + 4);  // idx 4..7
        unsigned la = m32 ? ca.y : ca.x;
        unsigned ia = m16 ? (la >> 16) : (la & 0xFFFFu);
        unsigned lb = m32 ? cb.y : cb.x;
        unsigned ib = m16 ? (lb >> 16) : (lb & 0xFFFFu);
        unsigned r0 = src[(size_t)ia * SLICE_DW + d];
        unsigned r1 = src[(size_t)ib * SLICE_DW + d];
        acc = pkadd(acc, r0);
        acc = pkadd(acc, r1);
    }
    if (p < pe) {  // one final chunk of 4
        uint2 ca = *(const uint2*)(nbr + p);
        unsigned la = m32 ? ca.y : ca.x;
        unsigned ia = m16 ? (la >> 16) : (la & 0xFFFFu);
        acc = pkadd(acc, src[(size_t)ia * SLICE_DW + d]);
    }
    // butterfly: sum the 4 lane-groups
    acc = pkadd(acc, (unsigned)__shfl_xor((int)acc, 16, 64));
    acc = pkadd(acc, (unsigned)__shfl_xor((int)acc, 32, 64));
    // compensation: padded entries added row 0 npad times (npad <= 3 per chunk rule)
    int npad = (pe - p0) - dg;
    {
        __half2 cc = __float2half2_rn((float)npad);
        __half2 a = *(__half2*)&acc;
        __half2 x = *(__half2*)&x0;
        a = __hsub2(a, __hmul2(cc, x));
        acc = *(unsigned*)&a;
    }
    float sc = scale[seg];
    unsigned pk = hpack(hlo(acc) * sc, hhi(acc) * sc);
    if (lane < 16) {
        dst[(size_t)seg * SLICE_DW + d] = pk;
        if (ckptB) ckptB[(size_t)seg * 1536 + (size_t)sl * SLICE_DW + d] = pk;
    }
}

// ---------------- final wavelet combine + relu split ----------------
// Checkpoints: fp16(inv_v*L) at out dwords v*1536 + slot*256 + sl*16 + [0,16).
// Recover L = ckpt * deg_v. 256 threads = 8 vertices, 4 feats/thread.
__global__ __launch_bounds__(256) void wavelet_out(const float* __restrict__ X,
                                                   const int* __restrict__ deg_v,
                                                   float* __restrict__ out) {
    int tid = blockIdx.x * 256 + threadIdx.x;
    int v = tid >> 5;
    int f4 = (tid & 31) * 4;           // feats f4..f4+3
    int sl = f4 >> 5;                  // feature slice
    int dl = (f4 & 31) >> 1;           // dword within slice
    float* row = out + (size_t)v * 1536;
    const unsigned* rowu = (const unsigned*)row;
    float degf = (float)deg_v[v];
    float4 L0v = *(const float4*)(X + (size_t)v * FEAT + f4);
    float l0[4] = {L0v.x, L0v.y, L0v.z, L0v.w};
    float L[5][4];
#pragma unroll
    for (int s = 0; s < 5; ++s) {
        int b = (s + 1) * 256 + sl * SLICE_DW + dl;
        unsigned d0 = rowu[b];
        unsigned d1 = rowu[b + 1];
        L[s][0] = hlo(d0) * degf;
        L[s][1] = hhi(d0) * degf;
        L[s][2] = hlo(d1) * degf;
        L[s][3] = hhi(d1) * degf;
    }
    float wv[6][4];
#pragma unroll
    for (int j = 0; j < 4; ++j) {
        wv[0][j] = l0[j] - L[0][j];
        wv[1][j] = L[0][j] - L[1][j];
        wv[2][j] = L[1][j] - L[2][j];
        wv[3][j] = L[2][j] - L[3][j];
        wv[4][j] = L[3][j] - L[4][j];
        wv[5][j] = L[4][j];
    }
    __syncthreads();
#pragma unroll
    for (int r = 0; r < 6; ++r) {
        float4 pp, mm;
        pp.x = fmaxf(wv[r][0], 0.f); mm.x = fmaxf(-wv[r][0], 0.f);
        pp.y = fmaxf(wv[r][1], 0.f); mm.y = fmaxf(-wv[r][1], 0.f);
        pp.z = fmaxf(wv[r][2], 0.f); mm.z = fmaxf(-wv[r][2], 0.f);
        pp.w = fmaxf(wv[r][3], 0.f); mm.w = fmaxf(-wv[r][3], 0.f);
        *(float4*)(row + r * 256 + f4) = pp;
        *(float4*)(row + r * 256 + 128 + f4) = mm;
    }
}

// ---------------- launch ----------------

extern "C" void kernel_launch(void* const* d_in, const int* in_sizes, int n_in,
                              void* d_out, int out_size, void* d_ws, size_t ws_size,
                              hipStream_t stream) {
    const float* X = (const float*)d_in[0];
    const int* vids = (const int*)d_in[1];
    const int* eids = (const int*)d_in[2];
    const int NNZ = in_sizes[1];       // 1048576
    const int V = in_sizes[0] / FEAT;  // 65536
    const int E = 16384;               // num_e
    float* out = (float*)d_out;

    const size_t ECAP = (size_t)NNZ + 4 * (size_t)E;  // padded e_nbr16 capacity
    const size_t VCAP = (size_t)NNZ + 4 * (size_t)V;  // padded v_nbr16 capacity

    char* w = (char*)d_ws;
    size_t o = 0;
    auto take = [&](size_t bytes) {
        void* p = (void*)(w + o);
        o = (o + bytes + 255) & ~(size_t)255;
        return p;
    };
    int* deg_v = (int*)take((size_t)(V + E) * 4);  // deg_v, deg_e contiguous
    int* deg_e = deg_v + V;
    int* off_e = (int*)take((size_t)(E + 1) * 4);
    int* off_v = (int*)take((size_t)(V + 1) * 4);
    int* cur_e = (int*)take((size_t)E * 4);
    int* cur_v = (int*)take((size_t)V * 4);
    float* inv_e = (float*)take((size_t)E * 4);
    float* inv_v = (float*)take((size_t)V * 4);
    unsigned short* e_nbr16 = (unsigned short*)take(ECAP * 2);
    unsigned short* v_nbr16 = (unsigned short*)take(VCAP * 2);
    unsigned* xs4 = (unsigned*)take((size_t)NSLICE * V * SLICE_DW * 4);  // 16.8 MB
    unsigned* es4 = (unsigned*)take((size_t)NSLICE * E * SLICE_DW * 4);  // 4.2 MB
    (void)ws_size;
    (void)n_in;
    (void)out_size;

    const unsigned XS_STRIDE = (unsigned)(V * SLICE_DW);
    const unsigned ES_STRIDE = (unsigned)(E * SLICE_DW);

    // 1) degrees
    hipMemsetAsync(deg_v, 0, (size_t)(V + E) * 4, stream);
    count_deg<<<(NNZ + 255) / 256, 256, 0, stream>>>(vids, eids, deg_v, deg_e, NNZ);

    // 2) padded offsets + cursors + 1/true-degree
    scan_pad<16384, 1024, 4><<<1, 1024, 0, stream>>>(deg_e, off_e, cur_e, inv_e);
    scan_pad<65536, 1024, 4><<<1, 1024, 0, stream>>>(deg_v, off_v, cur_v, inv_v);

    // 3) zero padded lists (pad entries = index 0, compensated in gather)
    hipMemsetAsync(e_nbr16, 0, ECAP * 2, stream);
    hipMemsetAsync(v_nbr16, 0, VCAP * 2, stream);

    // 4) adjacency lists (u16)
    fill_csr<<<(NNZ + 255) / 256, 256, 0, stream>>>(vids, eids, cur_v, cur_e,
                                                    v_nbr16, e_nbr16, NNZ);

    // 5) xs4 = fp16(X * inv_v), feature-sliced
    prescale<<<V * 64 / 256, 256, 0, stream>>>(X, inv_v, xs4, V);

    // 6) 16 diffusion steps, 4 feature slices phase-ordered via blockIdx.y.
    for (int k = 1; k <= 16; ++k) {
        gather_slice<<<dim3(E / 4, NSLICE), 256, 0, stream>>>(
            xs4, XS_STRIDE, es4, ES_STRIDE, off_e, deg_e, e_nbr16, inv_e, nullptr, E);
        unsigned* ck = nullptr;
        if (k == 1) ck = (unsigned*)out + 1 * 256;
        else if (k == 2) ck = (unsigned*)out + 2 * 256;
        else if (k == 4) ck = (unsigned*)out + 3 * 256;
        else if (k == 8) ck = (unsigned*)out + 4 * 256;
        else if (k == 16) ck = (unsigned*)out + 5 * 256;
        gather_slice<<<dim3(V / 4, NSLICE), 256, 0, stream>>>(
            es4, ES_STRIDE, xs4, XS_STRIDE, off_v, deg_v, v_nbr16, inv_v, ck, V);
    }

    // 7) wavelet combine + relu split, in place over out
    wavelet_out<<<V * 32 / 256, 256, 0, stream>>>(X, deg_v, out);
}

// Round 7
// 1124.992 us; speedup vs baseline: 3.1293x; 1.7834x over previous
//
#include <hip/hip_runtime.h>
#include <hip/hip_fp16.h>

// HyperScatteringModule: V=65536, E=16384, NNZ=1048576, F=128
#define FEAT 128

// ---------------- fp16 helpers (packed pairs: lo = even feat) ----------------

__device__ inline float hlo(unsigned u) {
    unsigned short s = (unsigned short)(u & 0xFFFFu);
    __half h = *(__half*)&s;
    return __half2float(h);
}
__device__ inline float hhi(unsigned u) {
    unsigned short s = (unsigned short)(u >> 16);
    __half h = *(__half*)&s;
    return __half2float(h);
}
__device__ inline unsigned hpack(float a, float b) {
    __half ha = __float2half_rn(a), hb = __float2half_rn(b);
    unsigned short ua = *(unsigned short*)&ha, ub = *(unsigned short*)&hb;
    return (unsigned)ua | ((unsigned)ub << 16);
}
__device__ inline unsigned pkadd(unsigned a, unsigned b) {
    __half2 ha = *(__half2*)&a, hb = *(__half2*)&b;
    __half2 r = __hadd2(ha, hb);
    return *(unsigned*)&r;
}

// ---------------- fp8 e4m3 helpers ----------------
#if __has_builtin(__builtin_amdgcn_cvt_pk_f32_fp8) && __has_builtin(__builtin_amdgcn_cvt_pk_fp8_f32)
typedef float floatx2 __attribute__((ext_vector_type(2)));
__device__ inline void fp8x2_to_f32(unsigned lo16, float& a, float& b) {
    floatx2 r = __builtin_amdgcn_cvt_pk_f32_fp8((int)lo16, false);
    a = r.x;
    b = r.y;
}
__device__ inline unsigned f32_to_fp8x2(float a, float b) {
    return (unsigned)__builtin_amdgcn_cvt_pk_fp8_f32(a, b, 0, false) & 0xFFFFu;
}
#else
// Fallback bit-twiddle codec for OCP e4m3fn
__device__ inline float fp8_dec1(unsigned u) {
    unsigned s = (u >> 7) & 1u, e = (u >> 3) & 15u, m = u & 7u;
    float v;
    if (e != 0) {
        unsigned bits = (s << 31) | ((e + 120u) << 23) | (m << 20);
        v = __uint_as_float(bits);
    } else {
        v = (float)m * 0.001953125f;  // m * 2^-9
        if (s) v = -v;
    }
    return v;
}
__device__ inline void fp8x2_to_f32(unsigned lo16, float& a, float& b) {
    a = fp8_dec1(lo16 & 0xFFu);
    b = fp8_dec1((lo16 >> 8) & 0xFFu);
}
__device__ inline unsigned fp8_enc1(float x) {
    float ax = fabsf(x);
    unsigned s = (__float_as_uint(x) >> 31) << 7;
    if (ax >= 448.f) return s | 0x7Eu;
    if (ax < 0.0009765625f) return s;  // < 2^-10 -> 0
    if (ax < 0.015625f) {              // subnormal: m = round(ax * 2^9)
        unsigned m = (unsigned)__builtin_rintf(ax * 512.f);
        if (m > 7u) m = 7u;
        return s | m;
    }
    unsigned bits = __float_as_uint(ax);
    int e32 = (int)((bits >> 23) & 255u) - 127;
    unsigned mant = bits & 0x7FFFFFu;
    unsigned m3 = mant >> 20;
    unsigned rem = mant & 0xFFFFFu;
    if (rem > 0x80000u || (rem == 0x80000u && (m3 & 1u))) {
        m3++;
        if (m3 == 8u) { m3 = 0; e32++; }
    }
    if (e32 > 8) return s | 0x7Eu;
    return s | ((unsigned)(e32 + 7) << 3) | m3;
}
__device__ inline unsigned f32_to_fp8x2(float a, float b) {
    return fp8_enc1(a) | (fp8_enc1(b) << 8);
}
#endif

// ---------------- CSR build ----------------

__global__ void count_deg(const int* __restrict__ vids, const int* __restrict__ eids,
                          int* __restrict__ deg_v, int* __restrict__ deg_e, int nnz) {
    int n = blockIdx.x * blockDim.x + threadIdx.x;
    if (n < nnz) {
        atomicAdd(&deg_v[vids[n]], 1);
        atomicAdd(&deg_e[eids[n]], 1);
    }
}

// Exclusive scan over CHUNK-padded degrees; off/cur = padded offsets, inv = 1/true_deg.
template <int N, int T, int CHUNK>
__global__ __launch_bounds__(T) void scan_pad(const int* __restrict__ deg,
                                              int* __restrict__ off,
                                              int* __restrict__ cur,
                                              float* __restrict__ inv) {
    __shared__ int partial[T];
    const int per = N / T;
    int tid = threadIdx.x;
    int base = tid * per;
    int dloc[per];
    int s = 0;
#pragma unroll
    for (int i = 0; i < per / 4; ++i) {
        int4 d4 = *(const int4*)(deg + base + 4 * i);
        dloc[4 * i] = d4.x; dloc[4 * i + 1] = d4.y;
        dloc[4 * i + 2] = d4.z; dloc[4 * i + 3] = d4.w;
        s += ((d4.x + CHUNK - 1) & ~(CHUNK - 1)) + ((d4.y + CHUNK - 1) & ~(CHUNK - 1)) +
             ((d4.z + CHUNK - 1) & ~(CHUNK - 1)) + ((d4.w + CHUNK - 1) & ~(CHUNK - 1));
    }
    partial[tid] = s;
    __syncthreads();
    for (int d = 1; d < T; d <<= 1) {
        int add = (tid >= d) ? partial[tid - d] : 0;
        __syncthreads();
        partial[tid] += add;
        __syncthreads();
    }
    int run = (tid > 0) ? partial[tid - 1] : 0;
#pragma unroll
    for (int i = 0; i < per / 4; ++i) {
        int o[4];
        float iv[4];
#pragma unroll
        for (int j = 0; j < 4; ++j) {
            int d = dloc[4 * i + j];
            o[j] = run;
            iv[j] = (d > 0) ? (1.0f / (float)d) : 0.0f;
            run += (d + CHUNK - 1) & ~(CHUNK - 1);
        }
        *(int4*)(off + base + 4 * i) = make_int4(o[0], o[1], o[2], o[3]);
        *(int4*)(cur + base + 4 * i) = make_int4(o[0], o[1], o[2], o[3]);
        *(float4*)(inv + base + 4 * i) = make_float4(iv[0], iv[1], iv[2], iv[3]);
    }
    if (tid == T - 1) off[N] = run;
}

// Fill padded slots with dummy row indices; zero the dummy rows of xs8/es.
__global__ void init_pad(int* __restrict__ nbrE, int nE, int dummyE,
                         int* __restrict__ nbrV, int nV, int dummyV,
                         unsigned* __restrict__ x8zero, unsigned* __restrict__ ezero) {
    int i = blockIdx.x * 256 + threadIdx.x;
    if (i < nE) nbrE[i] = dummyE;
    if (i < nV) nbrV[i] = dummyV;
    if (i < 32) x8zero[i] = 0u;  // 128B fp8 dummy row
    if (i < 64) ezero[i] = 0u;   // 256B fp16 dummy row
}

__global__ void fill_csr(const int* __restrict__ vids, const int* __restrict__ eids,
                         int* __restrict__ cur_v, int* __restrict__ cur_e,
                         int* __restrict__ v_nbr_e, int* __restrict__ e_nbr_v, int nnz) {
    int n = blockIdx.x * blockDim.x + threadIdx.x;
    if (n < nnz) {
        int v = vids[n], e = eids[n];
        int p = atomicAdd(&cur_e[e], 1);
        e_nbr_v[p] = v;
        int q = atomicAdd(&cur_v[v], 1);
        v_nbr_e[q] = e;
    }
}

// ---------------- prescale: xs8[v] = fp8(X[v] * inv_v), 4 feats/thread ----------------
__global__ __launch_bounds__(256) void prescale(const float* __restrict__ X,
                                                const float* __restrict__ inv_v,
                                                unsigned* __restrict__ xs8) {
    int tid = blockIdx.x * 256 + threadIdx.x;  // over V*32 dwords
    int v = tid >> 5, d = tid & 31;
    float sc = inv_v[v];
    float4 x = *(const float4*)(X + (size_t)v * FEAT + 4 * d);
    unsigned lo = f32_to_fp8x2(x.x * sc, x.y * sc);
    unsigned hi = f32_to_fp8x2(x.z * sc, x.w * sc);
    xs8[(size_t)v * 32 + d] = lo | (hi << 16);
}

// ---------------- v2e gather: fp8 rows -> fp32 acc -> fp16 es ----------------
// Wave per edge-segment (CHUNK=8 padded, dummy row = zeros). Lane owns 2 feats:
// loads ushort (2 fp8) at row*128 + lane*2; 1 VMEM (128B/wave) + cvt + 2 adds per visit.
__global__ __launch_bounds__(256) void gather_v2e(const unsigned short* __restrict__ xs8,
                                                  const int* __restrict__ offs,
                                                  const int* __restrict__ nbr,
                                                  const float* __restrict__ inv_e,
                                                  unsigned* __restrict__ es, int nseg) {
    int seg = __builtin_amdgcn_readfirstlane(blockIdx.x * 4 + (threadIdx.x >> 6));
    if (seg >= nseg) return;
    int lane = threadIdx.x & 63;
    int p = offs[seg], pend = offs[seg + 1];
    float ax = 0.f, ay = 0.f;
    for (; p < pend; p += 8) {
        int4 c0 = *(const int4*)(nbr + p);
        int4 c1 = *(const int4*)(nbr + p + 4);
        unsigned r0 = xs8[(size_t)c0.x * 64 + lane];
        unsigned r1 = xs8[(size_t)c0.y * 64 + lane];
        unsigned r2 = xs8[(size_t)c0.z * 64 + lane];
        unsigned r3 = xs8[(size_t)c0.w * 64 + lane];
        unsigned r4 = xs8[(size_t)c1.x * 64 + lane];
        unsigned r5 = xs8[(size_t)c1.y * 64 + lane];
        unsigned r6 = xs8[(size_t)c1.z * 64 + lane];
        unsigned r7 = xs8[(size_t)c1.w * 64 + lane];
        float a, b;
        fp8x2_to_f32(r0, a, b); ax += a; ay += b;
        fp8x2_to_f32(r1, a, b); ax += a; ay += b;
        fp8x2_to_f32(r2, a, b); ax += a; ay += b;
        fp8x2_to_f32(r3, a, b); ax += a; ay += b;
        fp8x2_to_f32(r4, a, b); ax += a; ay += b;
        fp8x2_to_f32(r5, a, b); ax += a; ay += b;
        fp8x2_to_f32(r6, a, b); ax += a; ay += b;
        fp8x2_to_f32(r7, a, b); ax += a; ay += b;
    }
    float sc = inv_e[seg];
    es[(size_t)seg * 64 + lane] = hpack(ax * sc, ay * sc);
}

// ---------------- e2v gather: fp16 es rows -> pkadd -> fp8 xs + fp16 ckpt ----------------
// Wave handles SPW=4 vertex-segments (CHUNK=4 padded, dummy row = zeros).
__global__ __launch_bounds__(256) void gather_e2v(const unsigned* __restrict__ es,
                                                  const int* __restrict__ offs,
                                                  const int* __restrict__ nbr,
                                                  const float* __restrict__ inv_v,
                                                  unsigned short* __restrict__ xs8,
                                                  unsigned* __restrict__ ckpt, int nseg) {
    int wv = __builtin_amdgcn_readfirstlane(blockIdx.x * 4 + (threadIdx.x >> 6));
    int lane = threadIdx.x & 63;
    int seg0 = wv * 4;
    if (seg0 >= nseg) return;
    int p = offs[seg0];
#pragma unroll
    for (int i = 0; i < 4; ++i) {
        int s = seg0 + i;
        int pend = offs[s + 1];
        unsigned acc = 0u;
        for (; p < pend; p += 4) {
            int4 c0 = *(const int4*)(nbr + p);
            unsigned r0 = es[(size_t)c0.x * 64 + lane];
            unsigned r1 = es[(size_t)c0.y * 64 + lane];
            unsigned r2 = es[(size_t)c0.z * 64 + lane];
            unsigned r3 = es[(size_t)c0.w * 64 + lane];
            acc = pkadd(acc, r0);
            acc = pkadd(acc, r1);
            acc = pkadd(acc, r2);
            acc = pkadd(acc, r3);
        }
        float sc = inv_v[s];
        float xl = hlo(acc) * sc, xh = hhi(acc) * sc;
        xs8[(size_t)s * 64 + lane] = (unsigned short)f32_to_fp8x2(xl, xh);
        if (ckpt) ckpt[(size_t)s * 1536 + lane] = hpack(xl, xh);
    }
}

// ---------------- final wavelet combine + relu split ----------------
// Checkpoints: fp16(inv_v*L) at out dwords v*1536 + slot*256 + [0,64).
// Recover L = ckpt * deg_v. 256 threads = 8 vertices, 4 feats/thread.
__global__ __launch_bounds__(256) void wavelet_out(const float* __restrict__ X,
                                                   const int* __restrict__ deg_v,
                                                   float* __restrict__ out) {
    int tid = blockIdx.x * 256 + threadIdx.x;
    int v = tid >> 5;
    int f4 = (tid & 31) * 4;
    float* row = out + (size_t)v * 1536;
    const unsigned* rowu = (const unsigned*)row;
    float degf = (float)deg_v[v];
    float4 L0v = *(const float4*)(X + (size_t)v * FEAT + f4);
    float l0[4] = {L0v.x, L0v.y, L0v.z, L0v.w};
    float L[5][4];
#pragma unroll
    for (int s = 0; s < 5; ++s) {
        unsigned d0 = rowu[(s + 1) * 256 + (f4 >> 1)];
        unsigned d1 = rowu[(s + 1) * 256 + (f4 >> 1) + 1];
        L[s][0] = hlo(d0) * degf;
        L[s][1] = hhi(d0) * degf;
        L[s][2] = hlo(d1) * degf;
        L[s][3] = hhi(d1) * degf;
    }
    float wv[6][4];
#pragma unroll
    for (int j = 0; j < 4; ++j) {
        wv[0][j] = l0[j] - L[0][j];
        wv[1][j] = L[0][j] - L[1][j];
        wv[2][j] = L[1][j] - L[2][j];
        wv[3][j] = L[2][j] - L[3][j];
        wv[4][j] = L[3][j] - L[4][j];
        wv[5][j] = L[4][j];
    }
    __syncthreads();
#pragma unroll
    for (int r = 0; r < 6; ++r) {
        float4 pp, mm;
        pp.x = fmaxf(wv[r][0], 0.f); mm.x = fmaxf(-wv[r][0], 0.f);
        pp.y = fmaxf(wv[r][1], 0.f); mm.y = fmaxf(-wv[r][1], 0.f);
        pp.z = fmaxf(wv[r][2], 0.f); mm.z = fmaxf(-wv[r][2], 0.f);
        pp.w = fmaxf(wv[r][3], 0.f); mm.w = fmaxf(-wv[r][3], 0.f);
        *(float4*)(row + r * 256 + f4) = pp;
        *(float4*)(row + r * 256 + 128 + f4) = mm;
    }
}

// ---------------- launch ----------------

extern "C" void kernel_launch(void* const* d_in, const int* in_sizes, int n_in,
                              void* d_out, int out_size, void* d_ws, size_t ws_size,
                              hipStream_t stream) {
    const float* X = (const float*)d_in[0];
    const int* vids = (const int*)d_in[1];
    const int* eids = (const int*)d_in[2];
    const int NNZ = in_sizes[1];       // 1048576
    const int V = in_sizes[0] / FEAT;  // 65536
    const int E = 16384;               // num_e
    float* out = (float*)d_out;

    const int NBRE_CAP = NNZ + E * 8;  // edge lists, CHUNK=8 padding
    const int NBRV_CAP = NNZ + V * 4;  // vertex lists, CHUNK=4 padding

    char* w = (char*)d_ws;
    size_t o = 0;
    auto take = [&](size_t bytes) {
        void* p = (void*)(w + o);
        o = (o + bytes + 255) & ~(size_t)255;
        return p;
    };
    int* deg_v = (int*)take((size_t)(V + E) * 4);  // deg_v, deg_e contiguous
    int* deg_e = deg_v + V;
    int* off_e = (int*)take((size_t)(E + 1) * 4);
    int* off_v = (int*)take((size_t)(V + 1) * 4);
    int* cur_e = (int*)take((size_t)E * 4);
    int* cur_v = (int*)take((size_t)V * 4);
    float* inv_e = (float*)take((size_t)E * 4);
    float* inv_v = (float*)take((size_t)V * 4);
    int* e_nbr_v = (int*)take((size_t)NBRE_CAP * 4);            // edge segs -> vertex rows
    int* v_nbr_e = (int*)take((size_t)NBRV_CAP * 4);            // vertex segs -> edge rows
    unsigned* xs8 = (unsigned*)take((size_t)(V + 1) * 32 * 4);  // fp8 [V+1][128] = 8.4MB
    unsigned* es = (unsigned*)take((size_t)(E + 1) * 64 * 4);   // fp16x2 [E+1][64] = 4.2MB
    (void)ws_size;
    (void)n_in;
    (void)out_size;

    // 1) degrees
    hipMemsetAsync(deg_v, 0, (size_t)(V + E) * 4, stream);
    count_deg<<<(NNZ + 255) / 256, 256, 0, stream>>>(vids, eids, deg_v, deg_e, NNZ);

    // 2) padded offsets + cursors + 1/true-degree
    scan_pad<16384, 1024, 8><<<1, 1024, 0, stream>>>(deg_e, off_e, cur_e, inv_e);
    scan_pad<65536, 1024, 4><<<1, 1024, 0, stream>>>(deg_v, off_v, cur_v, inv_v);

    // 3) dummy-fill padded lists (dummy -> zero row), zero dummy rows
    {
        int mx = NBRV_CAP > NBRE_CAP ? NBRV_CAP : NBRE_CAP;
        init_pad<<<(mx + 255) / 256, 256, 0, stream>>>(e_nbr_v, NBRE_CAP, V,
                                                       v_nbr_e, NBRV_CAP, E,
                                                       xs8 + (size_t)V * 32,
                                                       es + (size_t)E * 64);
    }

    // 4) adjacency lists
    fill_csr<<<(NNZ + 255) / 256, 256, 0, stream>>>(vids, eids, cur_v, cur_e,
                                                    v_nbr_e, e_nbr_v, NNZ);

    // 5) xs8 = fp8(X * inv_v)
    prescale<<<V * 32 / 256, 256, 0, stream>>>(X, inv_v, xs8);

    // 6) 16 diffusion steps; checkpoints k in {1,2,4,8,16} also write packed
    //    fp16 scaled level into out[v, slot, dwords 0:64] (recovered by *deg_v).
    for (int k = 1; k <= 16; ++k) {
        gather_v2e<<<E / 4, 256, 0, stream>>>((const unsigned short*)xs8, off_e,
                                              e_nbr_v, inv_e, es, E);
        unsigned* ck = nullptr;
        if (k == 1) ck = (unsigned*)out + 1 * 256;
        else if (k == 2) ck = (unsigned*)out + 2 * 256;
        else if (k == 4) ck = (unsigned*)out + 3 * 256;
        else if (k == 8) ck = (unsigned*)out + 4 * 256;
        else if (k == 16) ck = (unsigned*)out + 5 * 256;
        gather_e2v<<<V / 16, 256, 0, stream>>>(es, off_v, v_nbr_e, inv_v,
                                               (unsigned short*)xs8, ck, V);
    }

    // 7) wavelet combine + relu split, in place over out
    wavelet_out<<<V * 32 / 256, 256, 0, stream>>>(X, deg_v, out);
}

// Round 8
// 1059.230 us; speedup vs baseline: 3.3235x; 1.0621x over previous
//
#include <hip/hip_runtime.h>
#include <hip/hip_fp16.h>

// HyperScatteringModule: V=65536, E=16384, NNZ=1048576, F=128
#define FEAT 128

// ---------------- fp16 helpers (packed pairs: lo = even feat) ----------------

__device__ inline float hlo(unsigned u) {
    unsigned short s = (unsigned short)(u & 0xFFFFu);
    __half h = *(__half*)&s;
    return __half2float(h);
}
__device__ inline float hhi(unsigned u) {
    unsigned short s = (unsigned short)(u >> 16);
    __half h = *(__half*)&s;
    return __half2float(h);
}
__device__ inline unsigned hpack(float a, float b) {
    __half ha = __float2half_rn(a), hb = __float2half_rn(b);
    unsigned short ua = *(unsigned short*)&ha, ub = *(unsigned short*)&hb;
    return (unsigned)ua | ((unsigned)ub << 16);
}

// ---------------- fp8 e4m3 helpers ----------------
#if __has_builtin(__builtin_amdgcn_cvt_pk_f32_fp8) && __has_builtin(__builtin_amdgcn_cvt_pk_fp8_f32)
typedef float floatx2 __attribute__((ext_vector_type(2)));
__device__ inline void fp8x2_to_f32(unsigned lo16, float& a, float& b) {
    floatx2 r = __builtin_amdgcn_cvt_pk_f32_fp8((int)lo16, false);
    a = r.x;
    b = r.y;
}
__device__ inline unsigned f32_to_fp8x2(float a, float b) {
    return (unsigned)__builtin_amdgcn_cvt_pk_fp8_f32(a, b, 0, false) & 0xFFFFu;
}
#else
// Fallback bit-twiddle codec for OCP e4m3fn
__device__ inline float fp8_dec1(unsigned u) {
    unsigned s = (u >> 7) & 1u, e = (u >> 3) & 15u, m = u & 7u;
    float v;
    if (e != 0) {
        unsigned bits = (s << 31) | ((e + 120u) << 23) | (m << 20);
        v = __uint_as_float(bits);
    } else {
        v = (float)m * 0.001953125f;  // m * 2^-9
        if (s) v = -v;
    }
    return v;
}
__device__ inline void fp8x2_to_f32(unsigned lo16, float& a, float& b) {
    a = fp8_dec1(lo16 & 0xFFu);
    b = fp8_dec1((lo16 >> 8) & 0xFFu);
}
__device__ inline unsigned fp8_enc1(float x) {
    float ax = fabsf(x);
    unsigned s = (__float_as_uint(x) >> 31) << 7;
    if (ax >= 448.f) return s | 0x7Eu;
    if (ax < 0.0009765625f) return s;  // < 2^-10 -> 0
    if (ax < 0.015625f) {              // subnormal: m = round(ax * 2^9)
        unsigned m = (unsigned)__builtin_rintf(ax * 512.f);
        if (m > 7u) m = 7u;
        return s | m;
    }
    unsigned bits = __float_as_uint(ax);
    int e32 = (int)((bits >> 23) & 255u) - 127;
    unsigned mant = bits & 0x7FFFFFu;
    unsigned m3 = mant >> 20;
    unsigned rem = mant & 0xFFFFFu;
    if (rem > 0x80000u || (rem == 0x80000u && (m3 & 1u))) {
        m3++;
        if (m3 == 8u) { m3 = 0; e32++; }
    }
    if (e32 > 8) return s | 0x7Eu;
    return s | ((unsigned)(e32 + 7) << 3) | m3;
}
__device__ inline unsigned f32_to_fp8x2(float a, float b) {
    return fp8_enc1(a) | (fp8_enc1(b) << 8);
}
#endif

// ---------------- CSR build ----------------

__global__ void count_deg(const int* __restrict__ vids, const int* __restrict__ eids,
                          int* __restrict__ deg_v, int* __restrict__ deg_e, int nnz) {
    int n = blockIdx.x * blockDim.x + threadIdx.x;
    if (n < nnz) {
        atomicAdd(&deg_v[vids[n]], 1);
        atomicAdd(&deg_e[eids[n]], 1);
    }
}

// Exclusive scan over CHUNK-padded degrees; off/cur = padded offsets, inv = 1/true_deg.
template <int N, int T, int CHUNK>
__global__ __launch_bounds__(T) void scan_pad(const int* __restrict__ deg,
                                              int* __restrict__ off,
                                              int* __restrict__ cur,
                                              float* __restrict__ inv) {
    __shared__ int partial[T];
    const int per = N / T;
    int tid = threadIdx.x;
    int base = tid * per;
    int dloc[per];
    int s = 0;
#pragma unroll
    for (int i = 0; i < per / 4; ++i) {
        int4 d4 = *(const int4*)(deg + base + 4 * i);
        dloc[4 * i] = d4.x; dloc[4 * i + 1] = d4.y;
        dloc[4 * i + 2] = d4.z; dloc[4 * i + 3] = d4.w;
        s += ((d4.x + CHUNK - 1) & ~(CHUNK - 1)) + ((d4.y + CHUNK - 1) & ~(CHUNK - 1)) +
             ((d4.z + CHUNK - 1) & ~(CHUNK - 1)) + ((d4.w + CHUNK - 1) & ~(CHUNK - 1));
    }
    partial[tid] = s;
    __syncthreads();
    for (int d = 1; d < T; d <<= 1) {
        int add = (tid >= d) ? partial[tid - d] : 0;
        __syncthreads();
        partial[tid] += add;
        __syncthreads();
    }
    int run = (tid > 0) ? partial[tid - 1] : 0;
#pragma unroll
    for (int i = 0; i < per / 4; ++i) {
        int o[4];
        float iv[4];
#pragma unroll
        for (int j = 0; j < 4; ++j) {
            int d = dloc[4 * i + j];
            o[j] = run;
            iv[j] = (d > 0) ? (1.0f / (float)d) : 0.0f;
            run += (d + CHUNK - 1) & ~(CHUNK - 1);
        }
        *(int4*)(off + base + 4 * i) = make_int4(o[0], o[1], o[2], o[3]);
        *(int4*)(cur + base + 4 * i) = make_int4(o[0], o[1], o[2], o[3]);
        *(float4*)(inv + base + 4 * i) = make_float4(iv[0], iv[1], iv[2], iv[3]);
    }
    if (tid == T - 1) off[N] = run;
}

// Fill padded slots with dummy row indices; zero the dummy rows of xs8/es8.
__global__ void init_pad(int* __restrict__ nbrE, int nE, int dummyE,
                         int* __restrict__ nbrV, int nV, int dummyV,
                         unsigned* __restrict__ x8zero, unsigned* __restrict__ e8zero) {
    int i = blockIdx.x * 256 + threadIdx.x;
    if (i < nE) nbrE[i] = dummyE;
    if (i < nV) nbrV[i] = dummyV;
    if (i < 32) { x8zero[i] = 0u; e8zero[i] = 0u; }  // 128B fp8 dummy rows
}

__global__ void fill_csr(const int* __restrict__ vids, const int* __restrict__ eids,
                         int* __restrict__ cur_v, int* __restrict__ cur_e,
                         int* __restrict__ v_nbr_e, int* __restrict__ e_nbr_v, int nnz) {
    int n = blockIdx.x * blockDim.x + threadIdx.x;
    if (n < nnz) {
        int v = vids[n], e = eids[n];
        int p = atomicAdd(&cur_e[e], 1);
        e_nbr_v[p] = v;
        int q = atomicAdd(&cur_v[v], 1);
        v_nbr_e[q] = e;
    }
}

// ---------------- prescale: xs8[v] = fp8(X[v] * inv_v), 4 feats/thread ----------------
__global__ __launch_bounds__(256) void prescale(const float* __restrict__ X,
                                                const float* __restrict__ inv_v,
                                                unsigned* __restrict__ xs8) {
    int tid = blockIdx.x * 256 + threadIdx.x;  // over V*32 dwords
    int v = tid >> 5, d = tid & 31;
    float sc = inv_v[v];
    float4 x = *(const float4*)(X + (size_t)v * FEAT + 4 * d);
    unsigned lo = f32_to_fp8x2(x.x * sc, x.y * sc);
    unsigned hi = f32_to_fp8x2(x.z * sc, x.w * sc);
    xs8[(size_t)v * 32 + d] = lo | (hi << 16);
}

// ---------------- v2e gather: fp8 xs rows -> fp32 acc -> fp8 es ----------------
// Wave per edge-segment (CHUNK=8 padded, dummy row = zeros). Lane owns 2 feats:
// loads ushort (2 fp8) at row*128B + lane*2; 1 VMEM (128B/wave) per visit.
__global__ __launch_bounds__(256) void gather_v2e(const unsigned short* __restrict__ xs8,
                                                  const int* __restrict__ offs,
                                                  const int* __restrict__ nbr,
                                                  const float* __restrict__ inv_e,
                                                  unsigned short* __restrict__ es8, int nseg) {
    int seg = __builtin_amdgcn_readfirstlane(blockIdx.x * 4 + (threadIdx.x >> 6));
    if (seg >= nseg) return;
    int lane = threadIdx.x & 63;
    int p = offs[seg], pend = offs[seg + 1];
    float ax = 0.f, ay = 0.f;
    for (; p < pend; p += 8) {
        int4 c0 = *(const int4*)(nbr + p);
        int4 c1 = *(const int4*)(nbr + p + 4);
        unsigned r0 = xs8[(size_t)c0.x * 64 + lane];
        unsigned r1 = xs8[(size_t)c0.y * 64 + lane];
        unsigned r2 = xs8[(size_t)c0.z * 64 + lane];
        unsigned r3 = xs8[(size_t)c0.w * 64 + lane];
        unsigned r4 = xs8[(size_t)c1.x * 64 + lane];
        unsigned r5 = xs8[(size_t)c1.y * 64 + lane];
        unsigned r6 = xs8[(size_t)c1.z * 64 + lane];
        unsigned r7 = xs8[(size_t)c1.w * 64 + lane];
        float a, b;
        fp8x2_to_f32(r0, a, b); ax += a; ay += b;
        fp8x2_to_f32(r1, a, b); ax += a; ay += b;
        fp8x2_to_f32(r2, a, b); ax += a; ay += b;
        fp8x2_to_f32(r3, a, b); ax += a; ay += b;
        fp8x2_to_f32(r4, a, b); ax += a; ay += b;
        fp8x2_to_f32(r5, a, b); ax += a; ay += b;
        fp8x2_to_f32(r6, a, b); ax += a; ay += b;
        fp8x2_to_f32(r7, a, b); ax += a; ay += b;
    }
    float sc = inv_e[seg];
    es8[(size_t)seg * 64 + lane] = (unsigned short)f32_to_fp8x2(ax * sc, ay * sc);
}

// ---------------- e2v gather: fp8 es rows -> fp32 acc -> fp8 xs + fp16 ckpt ----------------
// Wave handles 4 vertex-segments (CHUNK=4 padded, dummy row = zeros).
__global__ __launch_bounds__(256) void gather_e2v(const unsigned short* __restrict__ es8,
                                                  const int* __restrict__ offs,
                                                  const int* __restrict__ nbr,
                                                  const float* __restrict__ inv_v,
                                                  unsigned short* __restrict__ xs8,
                                                  unsigned* __restrict__ ckpt, int nseg) {
    int wv = __builtin_amdgcn_readfirstlane(blockIdx.x * 4 + (threadIdx.x >> 6));
    int lane = threadIdx.x & 63;
    int seg0 = wv * 4;
    if (seg0 >= nseg) return;
    int p = offs[seg0];
#pragma unroll
    for (int i = 0; i < 4; ++i) {
        int s = seg0 + i;
        int pend = offs[s + 1];
        float ax = 0.f, ay = 0.f;
        for (; p < pend; p += 4) {
            int4 c0 = *(const int4*)(nbr + p);
            unsigned r0 = es8[(size_t)c0.x * 64 + lane];
            unsigned r1 = es8[(size_t)c0.y * 64 + lane];
            unsigned r2 = es8[(size_t)c0.z * 64 + lane];
            unsigned r3 = es8[(size_t)c0.w * 64 + lane];
            float a, b;
            fp8x2_to_f32(r0, a, b); ax += a; ay += b;
            fp8x2_to_f32(r1, a, b); ax += a; ay += b;
            fp8x2_to_f32(r2, a, b); ax += a; ay += b;
            fp8x2_to_f32(r3, a, b); ax += a; ay += b;
        }
        float sc = inv_v[s];
        float xl = ax * sc, xh = ay * sc;
        xs8[(size_t)s * 64 + lane] = (unsigned short)f32_to_fp8x2(xl, xh);
        if (ckpt) ckpt[(size_t)s * 1536 + lane] = hpack(xl, xh);
    }
}

// ---------------- final wavelet combine + relu split ----------------
// Checkpoints: fp16(inv_v*L) at out dwords v*1536 + slot*256 + [0,64).
// Recover L = ckpt * deg_v. 256 threads = 8 vertices, 4 feats/thread.
__global__ __launch_bounds__(256) void wavelet_out(const float* __restrict__ X,
                                                   const int* __restrict__ deg_v,
                                                   float* __restrict__ out) {
    int tid = blockIdx.x * 256 + threadIdx.x;
    int v = tid >> 5;
    int f4 = (tid & 31) * 4;
    float* row = out + (size_t)v * 1536;
    const unsigned* rowu = (const unsigned*)row;
    float degf = (float)deg_v[v];
    float4 L0v = *(const float4*)(X + (size_t)v * FEAT + f4);
    float l0[4] = {L0v.x, L0v.y, L0v.z, L0v.w};
    float L[5][4];
#pragma unroll
    for (int s = 0; s < 5; ++s) {
        unsigned d0 = rowu[(s + 1) * 256 + (f4 >> 1)];
        unsigned d1 = rowu[(s + 1) * 256 + (f4 >> 1) + 1];
        L[s][0] = hlo(d0) * degf;
        L[s][1] = hhi(d0) * degf;
        L[s][2] = hlo(d1) * degf;
        L[s][3] = hhi(d1) * degf;
    }
    float wv[6][4];
#pragma unroll
    for (int j = 0; j < 4; ++j) {
        wv[0][j] = l0[j] - L[0][j];
        wv[1][j] = L[0][j] - L[1][j];
        wv[2][j] = L[1][j] - L[2][j];
        wv[3][j] = L[2][j] - L[3][j];
        wv[4][j] = L[3][j] - L[4][j];
        wv[5][j] = L[4][j];
    }
    __syncthreads();
#pragma unroll
    for (int r = 0; r < 6; ++r) {
        float4 pp, mm;
        pp.x = fmaxf(wv[r][0], 0.f); mm.x = fmaxf(-wv[r][0], 0.f);
        pp.y = fmaxf(wv[r][1], 0.f); mm.y = fmaxf(-wv[r][1], 0.f);
        pp.z = fmaxf(wv[r][2], 0.f); mm.z = fmaxf(-wv[r][2], 0.f);
        pp.w = fmaxf(wv[r][3], 0.f); mm.w = fmaxf(-wv[r][3], 0.f);
        *(float4*)(row + r * 256 + f4) = pp;
        *(float4*)(row + r * 256 + 128 + f4) = mm;
    }
}

// ---------------- launch ----------------

extern "C" void kernel_launch(void* const* d_in, const int* in_sizes, int n_in,
                              void* d_out, int out_size, void* d_ws, size_t ws_size,
                              hipStream_t stream) {
    const float* X = (const float*)d_in[0];
    const int* vids = (const int*)d_in[1];
    const int* eids = (const int*)d_in[2];
    const int NNZ = in_sizes[1];       // 1048576
    const int V = in_sizes[0] / FEAT;  // 65536
    const int E = 16384;               // num_e
    float* out = (float*)d_out;

    const int NBRE_CAP = NNZ + E * 8;  // edge lists, CHUNK=8 padding
    const int NBRV_CAP = NNZ + V * 4;  // vertex lists, CHUNK=4 padding

    char* w = (char*)d_ws;
    size_t o = 0;
    auto take = [&](size_t bytes) {
        void* p = (void*)(w + o);
        o = (o + bytes + 255) & ~(size_t)255;
        return p;
    };
    int* deg_v = (int*)take((size_t)(V + E) * 4);  // deg_v, deg_e contiguous
    int* deg_e = deg_v + V;
    int* off_e = (int*)take((size_t)(E + 1) * 4);
    int* off_v = (int*)take((size_t)(V + 1) * 4);
    int* cur_e = (int*)take((size_t)E * 4);
    int* cur_v = (int*)take((size_t)V * 4);
    float* inv_e = (float*)take((size_t)E * 4);
    float* inv_v = (float*)take((size_t)V * 4);
    int* e_nbr_v = (int*)take((size_t)NBRE_CAP * 4);            // edge segs -> vertex rows
    int* v_nbr_e = (int*)take((size_t)NBRV_CAP * 4);            // vertex segs -> edge rows
    unsigned* xs8 = (unsigned*)take((size_t)(V + 1) * 32 * 4);  // fp8 [V+1][128] = 8.4MB
    unsigned* es8 = (unsigned*)take((size_t)(E + 1) * 32 * 4);  // fp8 [E+1][128] = 2.1MB
    (void)ws_size;
    (void)n_in;
    (void)out_size;

    // 1) degrees
    hipMemsetAsync(deg_v, 0, (size_t)(V + E) * 4, stream);
    count_deg<<<(NNZ + 255) / 256, 256, 0, stream>>>(vids, eids, deg_v, deg_e, NNZ);

    // 2) padded offsets + cursors + 1/true-degree
    scan_pad<16384, 1024, 8><<<1, 1024, 0, stream>>>(deg_e, off_e, cur_e, inv_e);
    scan_pad<65536, 1024, 4><<<1, 1024, 0, stream>>>(deg_v, off_v, cur_v, inv_v);

    // 3) dummy-fill padded lists (dummy -> zero row), zero dummy rows
    {
        int mx = NBRV_CAP > NBRE_CAP ? NBRV_CAP : NBRE_CAP;
        init_pad<<<(mx + 255) / 256, 256, 0, stream>>>(e_nbr_v, NBRE_CAP, V,
                                                       v_nbr_e, NBRV_CAP, E,
                                                       xs8 + (size_t)V * 32,
                                                       es8 + (size_t)E * 32);
    }

    // 4) adjacency lists
    fill_csr<<<(NNZ + 255) / 256, 256, 0, stream>>>(vids, eids, cur_v, cur_e,
                                                    v_nbr_e, e_nbr_v, NNZ);

    // 5) xs8 = fp8(X * inv_v)
    prescale<<<V * 32 / 256, 256, 0, stream>>>(X, inv_v, xs8);

    // 6) 16 diffusion steps; checkpoints k in {1,2,4,8,16} also write packed
    //    fp16 scaled level into out[v, slot, dwords 0:64] (recovered by *deg_v).
    for (int k = 1; k <= 16; ++k) {
        gather_v2e<<<E / 4, 256, 0, stream>>>((const unsigned short*)xs8, off_e,
                                              e_nbr_v, inv_e, (unsigned short*)es8, E);
        unsigned* ck = nullptr;
        if (k == 1) ck = (unsigned*)out + 1 * 256;
        else if (k == 2) ck = (unsigned*)out + 2 * 256;
        else if (k == 4) ck = (unsigned*)out + 3 * 256;
        else if (k == 8) ck = (unsigned*)out + 4 * 256;
        else if (k == 16) ck = (unsigned*)out + 5 * 256;
        gather_e2v<<<V / 16, 256, 0, stream>>>((const unsigned short*)es8, off_v,
                                               v_nbr_e, inv_v, (unsigned short*)xs8, ck, V);
    }

    // 7) wavelet combine + relu split, in place over out
    wavelet_out<<<V * 32 / 256, 256, 0, stream>>>(X, deg_v, out);
}